// Round 1
// baseline (154.246 us; speedup 1.0000x reference)
//
#include <hip/hip_runtime.h>
#include <math.h>

#define DIM 2048          // INPUT_DIM
#define NF 2048           // N_FORMULAS
#define LPF 16            // LITERALS_PER_FORMULA
#define LTOT (NF * LPF)   // 32768
#define BETA 0.4f
#define EPS 1.0f
#define DCHUNK 256
#define NCHUNKS (DIM / DCHUNK)   // 8

// ---------------------------------------------------------------------------
// Kernel A: per-formula partial reductions over a 256-row chunk of D.
// grid = (NF/256, NCHUNKS), block = 256. Lanes read consecutive formulas f
// -> fully coalesced row-major reads of both [D, F] inputs.
// ws layout: [chunk][3][NF] floats.
// ---------------------------------------------------------------------------
__global__ void partial_reduce_kernel(const float* __restrict__ lm,
                                      const float* __restrict__ frm,
                                      float* __restrict__ ws) {
    int f = blockIdx.x * blockDim.x + threadIdx.x;   // formula index
    int chunk = blockIdx.y;
    int d0 = chunk * DCHUNK;

    float sq = 0.0f, l1 = 0.0f, cnt = 0.0f;
    const float* lmp = lm + (size_t)d0 * NF + f;
    const float* frp = frm + (size_t)d0 * NF + f;
    #pragma unroll 4
    for (int i = 0; i < DCHUNK; ++i) {
        float x = lmp[(size_t)i * NF];
        float r = frp[(size_t)i * NF];
        sq  = fmaf(x * x, r, sq);
        l1  = fmaf(fabsf(x), r, l1);
        cnt += r;
    }
    float* wchunk = ws + (size_t)chunk * 3 * NF;
    wchunk[0 * NF + f] = sq;
    wchunk[1 * NF + f] = l1;
    wchunk[2 * NF + f] = cnt;
}

// ---------------------------------------------------------------------------
// Kernel B: combine chunks, compute per-formula elastic-net term, mean over F.
// 1 block of 256 threads; deterministic (fixed loop order + LDS tree).
// ---------------------------------------------------------------------------
__global__ void final_reduce_kernel(const float* __restrict__ ws,
                                    const float* __restrict__ alpha,
                                    float* __restrict__ out_scalar) {
    __shared__ float red[256];
    int t = threadIdx.x;
    float sig = 1.0f / (1.0f + expf(-alpha[0]));
    float w_l2 = (1.0f - sig) * 0.5f;
    float w_l1 = sig;

    float total = 0.0f;
    for (int k = 0; k < NF / 256; ++k) {
        int f = t + k * 256;
        float sq = 0.0f, l1 = 0.0f, cnt = 0.0f;
        for (int c = 0; c < NCHUNKS; ++c) {
            const float* wchunk = ws + (size_t)c * 3 * NF;
            sq  += wchunk[0 * NF + f];
            l1  += wchunk[1 * NF + f];
            cnt += wchunk[2 * NF + f];
        }
        float l2t = fabsf(sq / cnt - BETA * EPS * EPS);
        float l1t = fabsf(l1 / cnt - BETA * EPS);
        total += l2t * w_l2 + l1t * w_l1;
    }
    red[t] = total;
    __syncthreads();
    for (int s = 128; s > 0; s >>= 1) {
        if (t < s) red[t] += red[t + s];
        __syncthreads();
    }
    if (t == 0) out_scalar[0] = red[0] / (float)NF;
}

// ---------------------------------------------------------------------------
// Kernel C: expand formula columns to literal columns (the 536 MB write).
// One thread per output float4. The 4 literals inside one float4 share one
// formula (16 literals/formula = 4 float4s), so each thread does exactly one
// scalar load per input and two coalesced 16B stores.
// ---------------------------------------------------------------------------
__global__ void expand_kernel(const float* __restrict__ lm,
                              const float* __restrict__ frm,
                              float4* __restrict__ out0,
                              float4* __restrict__ out1) {
    int idx = blockIdx.x * blockDim.x + threadIdx.x;  // 0 .. D*LTOT/4 - 1
    int d  = idx >> 13;          // / (LTOT/4 = 8192)
    int l4 = idx & 8191;
    int f  = l4 >> 2;            // 4 float4s per formula

    float x = lm[(size_t)d * NF + f];
    float r = frm[(size_t)d * NF + f];
    float bin = (fabsf(x) > EPS) ? 1.0f : 0.0f;

    out0[idx] = make_float4(bin, bin, bin, bin);
    out1[idx] = make_float4(r, r, r, r);
}

extern "C" void kernel_launch(void* const* d_in, const int* in_sizes, int n_in,
                              void* d_out, int out_size, void* d_ws, size_t ws_size,
                              hipStream_t stream) {
    const float* lm    = (const float*)d_in[0];  // learnable_mask [D, F]
    const float* alpha = (const float*)d_in[1];  // elastic_net_alpha [1]
    const float* frm   = (const float*)d_in[2];  // formulas_random_mask [D, F]
    // d_in[3] = formula_id_per_literal (implicit: l // 16)

    float* out = (float*)d_out;
    float* ws  = (float*)d_ws;   // needs NCHUNKS*3*NF*4 = 192 KiB

    const size_t big = (size_t)DIM * LTOT;       // 67,108,864 per output
    float4* out0 = (float4*)out;                 // learnable_binary_mask
    float4* out1 = (float4*)(out + big);         // literals_random_mask
    float* out_scalar = out + 2 * big;           // elastic_net_reg

    // scalar reduction path (cheap): partials then deterministic combine
    dim3 gridA(NF / 256, NCHUNKS);
    partial_reduce_kernel<<<gridA, 256, 0, stream>>>(lm, frm, ws);
    final_reduce_kernel<<<1, 256, 0, stream>>>(ws, alpha, out_scalar);

    // big expansion (write-bound): one thread per float4
    const size_t n4 = big / 4;                   // 16,777,216
    expand_kernel<<<(unsigned)(n4 / 256), 256, 0, stream>>>(lm, frm, out0, out1);
}

// Round 3
// 132.687 us; speedup vs baseline: 1.1625x; 1.1625x over previous
//
#include <hip/hip_runtime.h>
#include <math.h>

#define DIM 2048          // INPUT_DIM
#define NF 2048           // N_FORMULAS
#define LPF 16            // LITERALS_PER_FORMULA
#define LTOT (NF * LPF)   // 32768
#define BETA 0.4f
#define EPS 1.0f

typedef float f32x4 __attribute__((ext_vector_type(4)));

// ---------------------------------------------------------------------------
// Fused kernel: expansion (the 537 MB write) + per-formula partial reduction.
// grid = (NF/64, ndch), block = 256.
//   - Each block owns 64 formulas (256 float4 output columns) and dch rows of d.
//   - Per d-iter: 2 broadcast scalar loads per 4-lane group (L1/L2-served),
//     two fully-coalesced 1KB/wave nontemporal 16B stores, and register
//     accumulation of {sum x^2*r, sum |x|*r, sum r} (VALU is nearly idle).
//   - Lane j==0 of each 4-lane group writes its formula's chunk-partials.
// ws layout: [ndch][3][NF] floats, then ws2[NF] floats after it.
// ---------------------------------------------------------------------------
__global__ void fused_expand_reduce(const float* __restrict__ lm,
                                    const float* __restrict__ frm,
                                    f32x4* __restrict__ out0,
                                    f32x4* __restrict__ out1,
                                    float* __restrict__ ws,
                                    int dch) {
    const int t = threadIdx.x;
    const int f = blockIdx.x * 64 + (t >> 2);      // formula this thread serves
    const int d0 = blockIdx.y * dch;

    float sq = 0.0f, l1 = 0.0f, cnt = 0.0f;
    const size_t obase = (size_t)blockIdx.x * 256 + t;   // float4 column index

    #pragma unroll 4
    for (int i = 0; i < dch; ++i) {
        const int d = d0 + i;
        const size_t in_off = ((size_t)d << 11) + f;     // d*NF + f
        float x = lm[in_off];
        float r = frm[in_off];
        float bin = (fabsf(x) > EPS) ? 1.0f : 0.0f;

        const size_t o = ((size_t)d << 13) + obase;      // d*(LTOT/4) + col
        f32x4 v0 = { bin, bin, bin, bin };
        f32x4 v1 = { r, r, r, r };
        __builtin_nontemporal_store(v0, &out0[o]);
        __builtin_nontemporal_store(v1, &out1[o]);

        sq  = fmaf(x * x, r, sq);
        l1  = fmaf(fabsf(x), r, l1);
        cnt += r;
    }

    if ((t & 3) == 0) {
        float* w = ws + (size_t)blockIdx.y * 3 * NF;
        w[0 * NF + f] = sq;
        w[1 * NF + f] = l1;
        w[2 * NF + f] = cnt;
    }
}

// ---------------------------------------------------------------------------
// Stage B: per-formula term from chunk partials. grid = NF/256 blocks.
// Reads ndch*3*NF floats (~1.5 MB) spread over 8 blocks, writes NF terms.
// ---------------------------------------------------------------------------
__global__ void formula_term_kernel(const float* __restrict__ ws,
                                    const float* __restrict__ alpha,
                                    float* __restrict__ ws2,
                                    int ndch) {
    const int f = blockIdx.x * blockDim.x + threadIdx.x;
    float sig = 1.0f / (1.0f + expf(-alpha[0]));
    float w_l2 = (1.0f - sig) * 0.5f;
    float w_l1 = sig;

    float sq = 0.0f, l1 = 0.0f, cnt = 0.0f;
    for (int c = 0; c < ndch; ++c) {
        const float* w = ws + (size_t)c * 3 * NF;
        sq  += w[0 * NF + f];
        l1  += w[1 * NF + f];
        cnt += w[2 * NF + f];
    }
    float l2t = fabsf(sq / cnt - BETA * EPS * EPS);
    float l1t = fabsf(l1 / cnt - BETA * EPS);
    ws2[f] = l2t * w_l2 + l1t * w_l1;
}

// ---------------------------------------------------------------------------
// Stage C: mean over formulas. 1 block, deterministic LDS tree.
// ---------------------------------------------------------------------------
__global__ void final_sum_kernel(const float* __restrict__ ws2,
                                 float* __restrict__ out_scalar) {
    __shared__ float red[256];
    const int t = threadIdx.x;
    float total = 0.0f;
    for (int k = 0; k < NF / 256; ++k)
        total += ws2[t + k * 256];
    red[t] = total;
    __syncthreads();
    for (int s = 128; s > 0; s >>= 1) {
        if (t < s) red[t] += red[t + s];
        __syncthreads();
    }
    if (t == 0) out_scalar[0] = red[0] / (float)NF;
}

extern "C" void kernel_launch(void* const* d_in, const int* in_sizes, int n_in,
                              void* d_out, int out_size, void* d_ws, size_t ws_size,
                              hipStream_t stream) {
    const float* lm    = (const float*)d_in[0];  // learnable_mask [D, F]
    const float* alpha = (const float*)d_in[1];  // elastic_net_alpha [1]
    const float* frm   = (const float*)d_in[2];  // formulas_random_mask [D, F]
    // d_in[3] = formula_id_per_literal (implicit: l // 16)

    float* out = (float*)d_out;
    float* ws  = (float*)d_ws;

    const size_t big = (size_t)DIM * LTOT;       // 67,108,864 per output
    f32x4* out0 = (f32x4*)out;                   // learnable_binary_mask
    f32x4* out1 = (f32x4*)(out + big);           // literals_random_mask
    float* out_scalar = out + 2 * big;           // elastic_net_reg

    // choose d-chunk count to fit ws: need (ndch*3*NF + NF)*4 bytes
    int ndch = 64;
    while (ndch > 1 && ((size_t)ndch * 3 * NF + NF) * 4 > ws_size) ndch >>= 1;
    const int dch = DIM / ndch;
    float* ws2 = ws + (size_t)ndch * 3 * NF;

    dim3 grid(NF / 64, ndch);
    fused_expand_reduce<<<grid, 256, 0, stream>>>(lm, frm, out0, out1, ws, dch);
    formula_term_kernel<<<NF / 256, 256, 0, stream>>>(ws, alpha, ws2, ndch);
    final_sum_kernel<<<1, 256, 0, stream>>>(ws2, out_scalar);
}